// Round 1
// baseline (557.810 us; speedup 1.0000x reference)
//
#include <hip/hip_runtime.h>

// Problem: B=32, S=577, D=768, H=12, Dh=64. ViT self-attention, fp32 in/out,
// bf16 MFMA compute (threshold 2.28e-2 is bf16-scaled).
#define NB 32
#define SEQ 577
#define SP 640      // padded seq (5*128, 20*32) so 128-tiles stay inside one batch
#define DM 768
#define NH 12
#define DH 64

typedef __attribute__((ext_vector_type(8))) short bf16x8;   // MFMA A/B frag (4 VGPRs)
typedef __attribute__((ext_vector_type(4))) float f32x4;    // MFMA C/D frag
typedef __attribute__((ext_vector_type(2))) unsigned int u32x2;
typedef unsigned short u16;

__device__ __forceinline__ u16 f2bf(float f) {  // RNE float->bf16
  unsigned int u = __builtin_bit_cast(unsigned int, f);
  u += 0x7fffu + ((u >> 16) & 1u);
  return (u16)(u >> 16);
}

__device__ __forceinline__ void g2l16(const void* g, void* lds) {
  // async global->LDS, 16B/lane; LDS dest = wave-uniform base + lane*16
  __builtin_amdgcn_global_load_lds(
      (const __attribute__((address_space(1))) void*)g,
      (__attribute__((address_space(3))) void*)lds, 16, 0, 0);
}

// ---- kernel 1: fp32 -> bf16 cast of hidden_states -------------------------
__global__ void cvt_x_kernel(const float* __restrict__ X, u16* __restrict__ Xb, int n4) {
  int i = blockIdx.x * 256 + threadIdx.x;
  if (i >= n4) return;
  f32x4 v = *reinterpret_cast<const f32x4*>(X + (size_t)i * 4);
  u32x2 p;
  p[0] = (unsigned)f2bf(v[0]) | ((unsigned)f2bf(v[1]) << 16);
  p[1] = (unsigned)f2bf(v[2]) | ((unsigned)f2bf(v[3]) << 16);
  *reinterpret_cast<u32x2*>(Xb + (size_t)i * 4) = p;
}

// ---- kernel 2: cast + transpose weights: Wt[qkv][n][k] --------------------
__global__ void cvt_w_kernel(const float* __restrict__ Wq, const float* __restrict__ Wk,
                             const float* __restrict__ Wv, u16* __restrict__ Wt) {
  int idx = blockIdx.x * 256 + threadIdx.x;  // 768*768 exactly covered
  int m = blockIdx.y;
  const float* W = (m == 0) ? Wq : (m == 1) ? Wk : Wv;
  int k = idx / DM, n = idx - k * DM;
  Wt[(size_t)m * DM * DM + (size_t)n * DM + k] = f2bf(W[idx]);
}

// ---- kernel 3: fused QKV GEMM (bf16 MFMA, 128x128 tile, BK=32) ------------
// Q,K -> [B,H,SP,DH] bf16 ; V -> transposed [B,H,DH,SP] bf16.
// Q gets (scale * log2e) folded in so attention can use exp2 directly.
__global__ __launch_bounds__(256)
void qkv_gemm_kernel(const u16* __restrict__ Xb, const u16* __restrict__ Wt,
                     const float* __restrict__ bq, const float* __restrict__ bk,
                     const float* __restrict__ bv,
                     u16* __restrict__ Qw, u16* __restrict__ Kw, u16* __restrict__ Vw) {
  // fragment-ordered LDS: [sub16-block][lane][8 bf16] -> linear lane*16B, conflict-free
  __shared__ alignas(16) u16 As[128 * 32];
  __shared__ alignas(16) u16 Bs[128 * 32];

  const int tid = threadIdx.x;
  const int lane = tid & 63;
  const int wid = tid >> 6;
  const int wr = wid >> 1, wc = wid & 1;   // 2x2 wave grid, 64x64 per wave
  const int l15 = lane & 15, lq = lane >> 4;

  const int mt = blockIdx.x;   // 160 M-tiles (32 batches * 5)
  const int nt = blockIdx.y;   // 6 N-tiles
  const int qkv = blockIdx.z;  // 0=Q 1=K 2=V

  const int b = mt / 5;
  const int t0 = (mt - b * 5) * 128;  // padded token base within batch
  const int n0 = nt * 128;

  const u16* Wm = Wt + (size_t)qkv * DM * DM;
  const float* bias = (qkv == 0) ? bq : (qkv == 1) ? bk : bv;

  // staging addresses (each wave stages sub-blocks wid and wid+4 of A and B)
  int tA0 = t0 + wid * 16 + l15;
  int tA1 = t0 + (wid + 4) * 16 + l15;
  int xr0 = b * SEQ + (tA0 < SEQ ? tA0 : SEQ - 1);  // clamp padded rows (finite, masked later)
  int xr1 = b * SEQ + (tA1 < SEQ ? tA1 : SEQ - 1);
  const u16* gA0 = Xb + (size_t)xr0 * DM + lq * 8;
  const u16* gA1 = Xb + (size_t)xr1 * DM + lq * 8;
  const u16* gB0 = Wm + (size_t)(n0 + wid * 16 + l15) * DM + lq * 8;
  const u16* gB1 = Wm + (size_t)(n0 + (wid + 4) * 16 + l15) * DM + lq * 8;
  u16* lA0 = &As[wid * 512];
  u16* lA1 = &As[(wid + 4) * 512];
  u16* lB0 = &Bs[wid * 512];
  u16* lB1 = &Bs[(wid + 4) * 512];

  f32x4 acc[4][4];
#pragma unroll
  for (int i = 0; i < 4; ++i)
#pragma unroll
    for (int j = 0; j < 4; ++j)
#pragma unroll
      for (int r = 0; r < 4; ++r) acc[i][j][r] = 0.0f;

  for (int k0 = 0; k0 < DM; k0 += 32) {
    g2l16(gA0 + k0, lA0);
    g2l16(gA1 + k0, lA1);
    g2l16(gB0 + k0, lB0);
    g2l16(gB1 + k0, lB1);
    __syncthreads();  // drains vmcnt(0): global_load_lds complete
    bf16x8 af[4], bfq[4];
#pragma unroll
    for (int i = 0; i < 4; ++i)
      af[i] = *reinterpret_cast<const bf16x8*>(&As[((wr * 4 + i) * 64 + lane) * 8]);
#pragma unroll
    for (int j = 0; j < 4; ++j)
      bfq[j] = *reinterpret_cast<const bf16x8*>(&Bs[((wc * 4 + j) * 64 + lane) * 8]);
#pragma unroll
    for (int i = 0; i < 4; ++i)
#pragma unroll
      for (int j = 0; j < 4; ++j)
        acc[i][j] = __builtin_amdgcn_mfma_f32_16x16x32_bf16(af[i], bfq[j], acc[i][j], 0, 0, 0);
    __syncthreads();  // protect LDS before next stage overwrites
  }

  const float sfold = 0.18033688011112042f;  // (1/sqrt(64)) * log2(e)
#pragma unroll
  for (int j = 0; j < 4; ++j) {
    int col = n0 + wc * 64 + j * 16 + l15;
    int h = col >> 6;
    int d = col & 63;
    float bb = bias[col];
#pragma unroll
    for (int i = 0; i < 4; ++i) {
      int trow = t0 + wr * 64 + i * 16 + lq * 4;  // C/D: row=(lane>>4)*4+r, col=lane&15
      if (qkv == 2) {
        // V transposed: Vt[b][h][d][t]; 4 consecutive t -> one 8B store
        float v0 = acc[i][j][0] + bb, v1 = acc[i][j][1] + bb;
        float v2 = acc[i][j][2] + bb, v3 = acc[i][j][3] + bb;
        u32x2 p;
        p[0] = (unsigned)f2bf(v0) | ((unsigned)f2bf(v1) << 16);
        p[1] = (unsigned)f2bf(v2) | ((unsigned)f2bf(v3) << 16);
        size_t o = ((size_t)(b * NH + h) * DH + d) * SP + trow;
        *reinterpret_cast<u32x2*>(Vw + o) = p;
      } else {
        u16* dst = ((qkv == 0) ? Qw : Kw) + ((size_t)(b * NH + h) * SP + trow) * DH + d;
#pragma unroll
        for (int r = 0; r < 4; ++r) {
          float v = acc[i][j][r] + bb;
          if (qkv == 0) v *= sfold;
          dst[r * DH] = f2bf(v);
        }
      }
    }
  }
}

// ---- kernel 4: flash attention ---------------------------------------------
// block = 4 waves, each wave owns 16 queries x full Dh=64; 32-key chunks;
// online softmax (exp2 domain; scale folded into Q); P transposed C->A layout
// through double-buffered per-wave LDS (1 barrier per chunk).
__global__ __launch_bounds__(256)
void attn_kernel(const u16* __restrict__ Qw, const u16* __restrict__ Kw,
                 const u16* __restrict__ Vw, float* __restrict__ out) {
  __shared__ alignas(16) u16 Pl[2][4][16 * 32];
  const int tid = threadIdx.x;
  const int lane = tid & 63;
  const int wid = tid >> 6;
  const int l15 = lane & 15, lq = lane >> 4;
  const int bh = blockIdx.y;
  const int b = bh / NH;
  const int h = bh - b * NH;
  const int q0 = blockIdx.x * 64 + wid * 16;

  const u16* Qb = Qw + (size_t)bh * SP * DH;
  const u16* Kb = Kw + (size_t)bh * SP * DH;
  const u16* Vb = Vw + (size_t)bh * DH * SP;

  bf16x8 qf0 = *reinterpret_cast<const bf16x8*>(&Qb[(q0 + l15) * DH + lq * 8]);
  bf16x8 qf1 = *reinterpret_cast<const bf16x8*>(&Qb[(q0 + l15) * DH + 32 + lq * 8]);

  float mrow[4], lrow[4];
  f32x4 acc[4];
#pragma unroll
  for (int r = 0; r < 4; ++r) { mrow[r] = -__builtin_inff(); lrow[r] = 0.0f; }
#pragma unroll
  for (int n = 0; n < 4; ++n)
#pragma unroll
    for (int r = 0; r < 4; ++r) acc[n][r] = 0.0f;

  int slot = 0;
  for (int c0 = 0; c0 < 608; c0 += 32) {  // 19 chunks of 32 keys (577 padded)
    bf16x8 k00 = *reinterpret_cast<const bf16x8*>(&Kb[(c0 + l15) * DH + lq * 8]);
    bf16x8 k01 = *reinterpret_cast<const bf16x8*>(&Kb[(c0 + l15) * DH + 32 + lq * 8]);
    bf16x8 k10 = *reinterpret_cast<const bf16x8*>(&Kb[(c0 + 16 + l15) * DH + lq * 8]);
    bf16x8 k11 = *reinterpret_cast<const bf16x8*>(&Kb[(c0 + 16 + l15) * DH + 32 + lq * 8]);
    f32x4 s0, s1;
#pragma unroll
    for (int r = 0; r < 4; ++r) { s0[r] = 0.0f; s1[r] = 0.0f; }
    s0 = __builtin_amdgcn_mfma_f32_16x16x32_bf16(qf0, k00, s0, 0, 0, 0);
    s0 = __builtin_amdgcn_mfma_f32_16x16x32_bf16(qf1, k01, s0, 0, 0, 0);
    s1 = __builtin_amdgcn_mfma_f32_16x16x32_bf16(qf0, k10, s1, 0, 0, 0);
    s1 = __builtin_amdgcn_mfma_f32_16x16x32_bf16(qf1, k11, s1, 0, 0, 0);
    // mask padded keys (col = lane&15 + subtile*16)
    if (c0 + l15 >= SEQ) {
#pragma unroll
      for (int r = 0; r < 4; ++r) s0[r] = -__builtin_inff();
    }
    if (c0 + 16 + l15 >= SEQ) {
#pragma unroll
      for (int r = 0; r < 4; ++r) s1[r] = -__builtin_inff();
    }
    u16* Ps = &Pl[slot][wid][0];
    float alpha[4];
#pragma unroll
    for (int r = 0; r < 4; ++r) {
      float v = fmaxf(s0[r], s1[r]);  // row max across 16 lanes (cols)
      v = fmaxf(v, __shfl_xor(v, 1));
      v = fmaxf(v, __shfl_xor(v, 2));
      v = fmaxf(v, __shfl_xor(v, 4));
      v = fmaxf(v, __shfl_xor(v, 8));
      float mn = fmaxf(mrow[r], v);
      alpha[r] = __builtin_amdgcn_exp2f(mrow[r] - mn);  // exp2(-inf)=0 on first chunk
      mrow[r] = mn;
      float p0 = __builtin_amdgcn_exp2f(s0[r] - mn);
      float p1 = __builtin_amdgcn_exp2f(s1[r] - mn);
      Ps[(lq * 4 + r) * 32 + l15] = f2bf(p0);        // P in [qrow][keycol] for A-frag reload
      Ps[(lq * 4 + r) * 32 + 16 + l15] = f2bf(p1);
      float ps = p0 + p1;
      ps += __shfl_xor(ps, 1);
      ps += __shfl_xor(ps, 2);
      ps += __shfl_xor(ps, 4);
      ps += __shfl_xor(ps, 8);
      lrow[r] = lrow[r] * alpha[r] + ps;
    }
    __syncthreads();  // P visible; double-buffered slots avoid a 2nd barrier
    bf16x8 pf = *reinterpret_cast<const bf16x8*>(&Ps[l15 * 32 + lq * 8]);
#pragma unroll
    for (int n = 0; n < 4; ++n) {
      bf16x8 vf = *reinterpret_cast<const bf16x8*>(&Vb[(n * 16 + l15) * SP + c0 + lq * 8]);
      f32x4 a = acc[n];
#pragma unroll
      for (int r = 0; r < 4; ++r) a[r] *= alpha[r];
      acc[n] = __builtin_amdgcn_mfma_f32_16x16x32_bf16(pf, vf, a, 0, 0, 0);
    }
    slot ^= 1;
  }

#pragma unroll
  for (int n = 0; n < 4; ++n)
#pragma unroll
    for (int r = 0; r < 4; ++r) {
      int t = q0 + lq * 4 + r;
      if (t < SEQ)
        out[((size_t)b * SEQ + t) * DM + h * DH + n * 16 + l15] = acc[n][r] / lrow[r];
    }
}

extern "C" void kernel_launch(void* const* d_in, const int* in_sizes, int n_in,
                              void* d_out, int out_size, void* d_ws, size_t ws_size,
                              hipStream_t stream) {
  (void)in_sizes; (void)n_in; (void)out_size; (void)ws_size;
  const float* X  = (const float*)d_in[0];
  const float* Wq = (const float*)d_in[1];
  const float* bq = (const float*)d_in[2];
  const float* Wk = (const float*)d_in[3];
  const float* bk = (const float*)d_in[4];
  const float* Wv = (const float*)d_in[5];
  const float* bv = (const float*)d_in[6];
  float* out = (float*)d_out;

  // workspace layout (bytes): Xb 28,366,848 | Wt 3,538,944 | Q/K/Vt 31,457,280 each
  char* ws = (char*)d_ws;
  u16* Xb = (u16*)ws;
  u16* Wt = (u16*)(ws + 28366848);
  u16* Qw = (u16*)(ws + 28366848 + 3538944);
  u16* Kw = Qw + (size_t)NB * NH * SP * DH;
  u16* Vw = Kw + (size_t)NB * NH * SP * DH;

  cvt_x_kernel<<<dim3(13848), 256, 0, stream>>>(X, Xb, 3545088);
  cvt_w_kernel<<<dim3(2304, 3), 256, 0, stream>>>(Wq, Wk, Wv, Wt);
  qkv_gemm_kernel<<<dim3(160, 6, 3), 256, 0, stream>>>(Xb, Wt, bq, bk, bv, Qw, Kw, Vw);
  attn_kernel<<<dim3(10, NB * NH), 256, 0, stream>>>(Qw, Kw, Vw, out);
}